// Round 1
// baseline (1116.332 us; speedup 1.0000x reference)
//
#include <hip/hip_runtime.h>

// GTrXL fused pipeline, bf16 MFMA everywhere (gfx950).
// Stages: wtT/cvt -> LN1 -> GEMM kv/q/rpos -> vT -> fused attn -> proj ->
//         GRU1 -> LN2 -> MLP -> GRU2 -> d_out.

typedef __bf16 bf16_t;
typedef __bf16 bf16x4 __attribute__((ext_vector_type(4)));
typedef __bf16 bf16x8 __attribute__((ext_vector_type(8)));
typedef float f32x4 __attribute__((ext_vector_type(4)));

typedef __attribute__((address_space(1))) const void* GPtr;
typedef __attribute__((address_space(3))) void* LPtr;

// ---------------- fp32 -> bf16 convert ----------------
__global__ __launch_bounds__(256) void cvt_kernel(const float* __restrict__ in,
                                                  bf16_t* __restrict__ out, int n4) {
  int i = blockIdx.x * 256 + threadIdx.x;
  if (i >= n4) return;
  f32x4 v = ((const f32x4*)in)[i];
  bf16x4 o;
  o[0] = (bf16_t)v[0]; o[1] = (bf16_t)v[1]; o[2] = (bf16_t)v[2]; o[3] = (bf16_t)v[3];
  ((bf16x4*)out)[i] = o;
}

// ---------------- weight transpose + convert: W[K][N] f32 -> WT[N][K] bf16 ----------------
__global__ __launch_bounds__(256) void wt_transpose(const float* __restrict__ W,
                                                    bf16_t* __restrict__ WT, int K, int N) {
  __shared__ float t[64][65];
  int n0 = blockIdx.x * 64, k0 = blockIdx.y * 64;
  int tid = threadIdx.x;
  int c = tid & 63, r0 = tid >> 6;
  #pragma unroll
  for (int p = 0; p < 16; ++p) {
    int r = r0 + p * 4;
    t[r][c] = W[(size_t)(k0 + r) * N + n0 + c];
  }
  __syncthreads();
  #pragma unroll
  for (int p = 0; p < 16; ++p) {
    int r = r0 + p * 4;  // r = n index, c = k index
    WT[(size_t)(n0 + r) * K + k0 + c] = (bf16_t)t[c][r];
  }
}

// ---------------- LayerNorm over D=1024, optional row-concat of two sources ----------------
__global__ __launch_bounds__(256) void ln_kernel(const float* __restrict__ srcA,
                                                 const float* __restrict__ srcB, int splitRow,
                                                 const float* __restrict__ g,
                                                 const float* __restrict__ be,
                                                 bf16_t* __restrict__ out) {
  const int row = blockIdx.x, tid = threadIdx.x;
  const float* src = (srcB != nullptr && row >= splitRow)
                         ? srcB + (size_t)(row - splitRow) * 1024
                         : srcA + (size_t)row * 1024;
  f32x4 x = ((const f32x4*)src)[tid];
  __shared__ float red[8];
  float s = x[0] + x[1] + x[2] + x[3];
  #pragma unroll
  for (int o = 32; o; o >>= 1) s += __shfl_down(s, o);
  if ((tid & 63) == 0) red[tid >> 6] = s;
  __syncthreads();
  if (tid == 0) red[4] = (red[0] + red[1] + red[2] + red[3]) * (1.f / 1024.f);
  __syncthreads();
  const float mean = red[4];
  f32x4 d = x - mean;
  float s2 = d[0] * d[0] + d[1] * d[1] + d[2] * d[2] + d[3] * d[3];
  #pragma unroll
  for (int o = 32; o; o >>= 1) s2 += __shfl_down(s2, o);
  if ((tid & 63) == 0) red[tid >> 6] = s2;
  __syncthreads();
  if (tid == 0) red[5] = rsqrtf((red[0] + red[1] + red[2] + red[3]) * (1.f / 1024.f) + 1e-5f);
  __syncthreads();
  const float rstd = red[5];
  f32x4 gg = ((const f32x4*)g)[tid], bb = ((const f32x4*)be)[tid];
  bf16x4 o4;
  #pragma unroll
  for (int j = 0; j < 4; ++j) o4[j] = (bf16_t)(d[j] * rstd * gg[j] + bb[j]);
  ((bf16x4*)(out + (size_t)row * 1024))[tid] = o4;
}

// ---------------- generic bf16 MFMA GEMM: C[M][N] = act(A[M][K] @ BT[N][K]^T + bias + Cacc) ----------------
// act: 0 none, 1 relu, 2 sigmoid, 3 tanh
__global__ __launch_bounds__(256) void gemm_bf16(const bf16_t* __restrict__ A,
                                                 const bf16_t* __restrict__ BT,
                                                 float* __restrict__ Cf, bf16_t* __restrict__ Cb,
                                                 const float* __restrict__ Cacc,
                                                 const float* __restrict__ bias, float bscale,
                                                 int M, int N, int K, int act) {
  __shared__ bf16_t As[128 * 32];
  __shared__ bf16_t Bs[128 * 32];
  const int tid = threadIdx.x, lane = tid & 63, wid = tid >> 6;
  const int m0 = blockIdx.y * 128, n0 = blockIdx.x * 128;
  const int wm = (wid >> 1) * 64, wn = (wid & 1) * 64;
  const int mrow = lane & 15, kq = lane >> 4;
  f32x4 acc[4][4] = {};
  for (int k0 = 0; k0 < K; k0 += 32) {
    #pragma unroll
    for (int p = 0; p < 2; ++p) {
      int cbase = p * 256 + wid * 64;
      int c = cbase + lane;
      const bf16_t* ga = A + (size_t)(m0 + (c >> 2)) * K + k0 + (c & 3) * 8;
      const bf16_t* gb = BT + (size_t)(n0 + (c >> 2)) * K + k0 + (c & 3) * 8;
      __builtin_amdgcn_global_load_lds((GPtr)ga, (LPtr)(&As[cbase * 8]), 16, 0, 0);
      __builtin_amdgcn_global_load_lds((GPtr)gb, (LPtr)(&Bs[cbase * 8]), 16, 0, 0);
    }
    __syncthreads();
    bf16x8 af[4], bfr[4];
    #pragma unroll
    for (int i = 0; i < 4; ++i) {
      af[i] = *(const bf16x8*)&As[(wm + i * 16 + mrow) * 32 + kq * 8];
      bfr[i] = *(const bf16x8*)&Bs[(wn + i * 16 + mrow) * 32 + kq * 8];
    }
    #pragma unroll
    for (int i = 0; i < 4; ++i)
      #pragma unroll
      for (int j = 0; j < 4; ++j)
        acc[i][j] = __builtin_amdgcn_mfma_f32_16x16x32_bf16(af[i], bfr[j], acc[i][j], 0, 0, 0);
    __syncthreads();
  }
  #pragma unroll
  for (int i = 0; i < 4; ++i) {
    #pragma unroll
    for (int j = 0; j < 4; ++j) {
      int colb = n0 + wn + j * 16 + mrow;
      float bv = bias ? bias[colb] * bscale : 0.f;
      #pragma unroll
      for (int r2 = 0; r2 < 4; ++r2) {
        int row = m0 + wm + i * 16 + kq * 4 + r2;
        size_t idx = (size_t)row * N + colb;
        float vv = acc[i][j][r2] + bv;
        if (Cacc) vv += Cacc[idx];
        if (act == 1) vv = fmaxf(vv, 0.f);
        else if (act == 2) vv = 1.f / (1.f + __expf(-vv));
        else if (act == 3) vv = tanhf(vv);
        if (Cf) Cf[idx] = vv;
        if (Cb) Cb[idx] = (bf16_t)vv;
      }
    }
  }
}

// ---------------- value transpose: kv val-half -> vT[(b*16+h)*64+d][f] ----------------
__global__ __launch_bounds__(256) void vT_kernel(const bf16_t* __restrict__ kv,
                                                 bf16_t* __restrict__ vT) {
  int ft = blockIdx.x;       // 16 tiles of 64 f
  int bh = blockIdx.y;       // b*16+h
  int b = bh >> 4, h = bh & 15;
  __shared__ bf16_t t[64][68];
  int tid = threadIdx.x;
  {
    int dq = (tid & 15) * 4, fr = tid >> 4;
    #pragma unroll
    for (int p = 0; p < 4; ++p) {
      int fi = fr + p * 16;
      const bf16_t* src = kv + ((size_t)((ft * 64 + fi) * 8 + b)) * 2048 + 1024 + h * 64 + dq;
      *(bf16x4*)&t[fi][dq] = *(const bf16x4*)src;
    }
  }
  __syncthreads();
  {
    int fl = tid & 63, dr = tid >> 6;
    #pragma unroll
    for (int p = 0; p < 16; ++p) {
      int d = dr + p * 4;
      vT[((size_t)(bh * 64 + d)) * 1024 + ft * 64 + fl] = t[fl][d];
    }
  }
}

// ---------------- fused rel-pos attention, one block per (b,h,s-tile of 16) ----------------
__global__ __launch_bounds__(256) void attn_kernel(const bf16_t* __restrict__ q,
                                                   const bf16_t* __restrict__ kv,
                                                   const bf16_t* __restrict__ rpos,
                                                   const bf16_t* __restrict__ vT,
                                                   const float* __restrict__ u,
                                                   const float* __restrict__ v,
                                                   bf16_t* __restrict__ av) {
  const int st = blockIdx.x, h = blockIdx.y, b = blockIdx.z;
  const int s0 = st * 16;
  const int tid = threadIdx.x, lane = tid & 63, wid = tid >> 6;
  const int mrow = lane & 15, kq = lane >> 4;

  __shared__ bf16_t sc[16][1032];  // scores, then exp-probs (in place)
  __shared__ bf16_t qu[16][72];
  __shared__ bf16_t qv[16][72];
  __shared__ float rowsum[16];

  {  // stage q+u / q+v
    const int sl = tid >> 4, dq = (tid & 15) * 4;
    const bf16_t* qp = q + ((size_t)((s0 + sl) * 8 + b)) * 1024 + h * 64 + dq;
    bf16x4 q4 = *(const bf16x4*)qp;
    f32x4 uu = *(const f32x4*)(u + h * 64 + dq);
    f32x4 vv = *(const f32x4*)(v + h * 64 + dq);
    #pragma unroll
    for (int j = 0; j < 4; ++j) {
      float qf = (float)q4[j];
      qu[sl][dq + j] = (bf16_t)(qf + uu[j]);
      qv[sl][dq + j] = (bf16_t)(qf + vv[j]);
    }
  }
  __syncthreads();

  bf16x8 afu[2], afv[2];
  afu[0] = *(const bf16x8*)&qu[mrow][kq * 8];
  afu[1] = *(const bf16x8*)&qu[mrow][32 + kq * 8];
  afv[0] = *(const bf16x8*)&qv[mrow][kq * 8];
  afv[1] = *(const bf16x8*)&qv[mrow][32 + kq * 8];

  // content scores: sc[s][f] = (q+u).key[f]
  for (int nf = wid; nf < 64; nf += 4) {
    int fl = nf * 16 + mrow;
    const bf16_t* kp = kv + ((size_t)(fl * 8 + b)) * 2048 + h * 64 + kq * 8;
    bf16x8 b0 = *(const bf16x8*)kp;
    bf16x8 b1 = *(const bf16x8*)(kp + 32);
    f32x4 c = {0.f, 0.f, 0.f, 0.f};
    c = __builtin_amdgcn_mfma_f32_16x16x32_bf16(afu[0], b0, c, 0, 0, 0);
    c = __builtin_amdgcn_mfma_f32_16x16x32_bf16(afu[1], b1, c, 0, 0, 0);
    #pragma unroll
    for (int r2 = 0; r2 < 4; ++r2) sc[kq * 4 + r2][fl] = (bf16_t)c[r2];
  }
  __syncthreads();

  // position scores via rel-shift scatter: raw[s][j] adds into sc[s][f= j-511+s]
  for (int jf = wid; jf < 64; jf += 4) {
    int jl = jf * 16 + mrow;
    const bf16_t* rp = rpos + (size_t)jl * 1024 + h * 64 + kq * 8;
    bf16x8 b0 = *(const bf16x8*)rp;
    bf16x8 b1 = *(const bf16x8*)(rp + 32);
    f32x4 c = {0.f, 0.f, 0.f, 0.f};
    c = __builtin_amdgcn_mfma_f32_16x16x32_bf16(afv[0], b0, c, 0, 0, 0);
    c = __builtin_amdgcn_mfma_f32_16x16x32_bf16(afv[1], b1, c, 0, 0, 0);
    #pragma unroll
    for (int r2 = 0; r2 < 4; ++r2) {
      int row = kq * 4 + r2;
      int f = jl - 511 + s0 + row;
      if (f >= 0 && f < 1024) {
        float old = (float)sc[row][f];
        sc[row][f] = (bf16_t)(old + c[r2]);
      }
    }
  }
  __syncthreads();

  // masked softmax per row (wave w owns rows 4w..4w+3); in-place exp, fold 1/sum later
  for (int rr = 0; rr < 4; ++rr) {
    int row = wid * 4 + rr;
    int fmx = s0 + row + 512;  // f <= s+PREV unmasked
    float vals[16];
    float mx = -1e30f;
    #pragma unroll
    for (int i = 0; i < 16; ++i) {
      int f = lane + i * 64;
      float x = (float)sc[row][f] * 0.125f;  // SCALE = 1/sqrt(64)
      vals[i] = x;
      if (f <= fmx) mx = fmaxf(mx, x);
    }
    #pragma unroll
    for (int o = 32; o; o >>= 1) mx = fmaxf(mx, __shfl_xor(mx, o));
    float sum = 0.f;
    #pragma unroll
    for (int i = 0; i < 16; ++i) {
      int f = lane + i * 64;
      float e = (f <= fmx) ? __expf(vals[i] - mx) : 0.f;
      sum += e;
      sc[row][f] = (bf16_t)e;
    }
    #pragma unroll
    for (int o = 32; o; o >>= 1) sum += __shfl_xor(sum, o);
    if (lane == 0) rowsum[row] = sum;
  }
  __syncthreads();

  // AV: out[s][d] = sum_f p[s][f] * value[f][d]; wave w covers d block w*16
  {
    int dl = wid * 16 + mrow;
    const bf16_t* vp = vT + ((size_t)((b * 16 + h) * 64 + dl)) * 1024;
    f32x4 acc = {0.f, 0.f, 0.f, 0.f};
    for (int kk = 0; kk < 32; ++kk) {
      bf16x8 af = *(const bf16x8*)&sc[mrow][kk * 32 + kq * 8];
      bf16x8 bv = *(const bf16x8*)(vp + kk * 32 + kq * 8);
      acc = __builtin_amdgcn_mfma_f32_16x16x32_bf16(af, bv, acc, 0, 0, 0);
    }
    #pragma unroll
    for (int r2 = 0; r2 < 4; ++r2) {
      int sl = kq * 4 + r2;
      float ov = acc[r2] / rowsum[sl];
      av[((size_t)((s0 + sl) * 8 + b)) * 1024 + h * 64 + dl] = (bf16_t)ov;
    }
  }
}

// ---------------- elementwise ----------------
__global__ __launch_bounds__(256) void ew_rx_kernel(const float* __restrict__ r,
                                                    const float* __restrict__ x,
                                                    bf16_t* __restrict__ out, int n4) {
  int i = blockIdx.x * 256 + threadIdx.x;
  if (i >= n4) return;
  f32x4 rr = ((const f32x4*)r)[i], xx = ((const f32x4*)x)[i];
  bf16x4 o;
  #pragma unroll
  for (int j = 0; j < 4; ++j) o[j] = (bf16_t)(rr[j] * xx[j]);
  ((bf16x4*)out)[i] = o;
}

__global__ __launch_bounds__(256) void ew_combine_kernel(const float* __restrict__ z,
                                                         const float* __restrict__ h,
                                                         const float* __restrict__ x,
                                                         float* __restrict__ outf,
                                                         bf16_t* __restrict__ outb, int n4) {
  int i = blockIdx.x * 256 + threadIdx.x;
  if (i >= n4) return;
  f32x4 zz = ((const f32x4*)z)[i], hh = ((const f32x4*)h)[i], xx = ((const f32x4*)x)[i];
  f32x4 o = xx + zz * (hh - xx);
  if (outf) ((f32x4*)outf)[i] = o;
  if (outb) {
    bf16x4 ob;
    #pragma unroll
    for (int j = 0; j < 4; ++j) ob[j] = (bf16_t)o[j];
    ((bf16x4*)outb)[i] = ob;
  }
}

// ---------------- host ----------------
extern "C" void kernel_launch(void* const* d_in, const int* in_sizes, int n_in,
                              void* d_out, int out_size, void* d_ws, size_t ws_size,
                              hipStream_t stream) {
  const float* inputs = (const float*)d_in[0];
  const float* pos_emb = (const float*)d_in[1];
  const float* memory = (const float*)d_in[2];
  const float* u = (const float*)d_in[3];
  const float* v = (const float*)d_in[4];
  // d_in[5] = mask (recomputed analytically in-kernel)
  const float* Wkv = (const float*)d_in[6];
  const float* bkv = (const float*)d_in[7];
  const float* Wq = (const float*)d_in[8];
  const float* bq = (const float*)d_in[9];
  const float* Wpos = (const float*)d_in[10];
  const float* bpos = (const float*)d_in[11];
  const float* Wproj = (const float*)d_in[12];
  const float* bproj = (const float*)d_in[13];
  const float* ln1_g = (const float*)d_in[14];
  const float* ln1_b = (const float*)d_in[15];
  const float* ln2_g = (const float*)d_in[16];
  const float* ln2_b = (const float*)d_in[17];
  const float* g1W[6] = {(const float*)d_in[18], (const float*)d_in[19], (const float*)d_in[20],
                         (const float*)d_in[21], (const float*)d_in[22], (const float*)d_in[23]};
  const float* g1_bg = (const float*)d_in[24];
  const float* g2W[6] = {(const float*)d_in[25], (const float*)d_in[26], (const float*)d_in[27],
                         (const float*)d_in[28], (const float*)d_in[29], (const float*)d_in[30]};
  const float* g2_bg = (const float*)d_in[31];
  const float* mlp_W1 = (const float*)d_in[32];
  const float* mlp_b1 = (const float*)d_in[33];
  const float* mlp_W2 = (const float*)d_in[34];
  const float* mlp_b2 = (const float*)d_in[35];

  char* ws = (char*)d_ws;
  const size_t MB = 1ull << 20;
  // region1 (attention temps; aliased by gate temps afterwards — lifetimes verified)
  bf16_t* x1 = (bf16_t*)(ws + 0);           // 16MB, rows = s*8+b over FULL
  bf16_t* kvb = (bf16_t*)(ws + 16 * MB);    // 32MB (8192 x 2048)
  bf16_t* qb = (bf16_t*)(ws + 48 * MB);     // 8MB  (4096 x 1024)
  bf16_t* peb = (bf16_t*)(ws + 56 * MB);    // 2MB
  bf16_t* rposb = (bf16_t*)(ws + 58 * MB);  // 2MB
  bf16_t* vTb = (bf16_t*)(ws + 60 * MB);    // 16MB
  bf16_t* avb = (bf16_t*)(ws + 76 * MB);    // 8MB
  // gate temps (alias region1, all region1 buffers dead by first use)
  float* rbuf = (float*)(ws + 0);           // 16MB
  float* zbuf = (float*)(ws + 16 * MB);     // 16MB
  float* hbuf = (float*)(ws + 32 * MB);     // 16MB
  bf16_t* rxb = (bf16_t*)(ws + 48 * MB);    // 8MB
  float* o1f = (float*)(ws + 56 * MB);      // 16MB
  bf16_t* o1b = (bf16_t*)(ws + 72 * MB);    // 8MB
  // fixed
  bf16_t* a1b = (bf16_t*)(ws + 84 * MB);
  bf16_t* inb = (bf16_t*)(ws + 92 * MB);
  bf16_t* x2b = (bf16_t*)(ws + 100 * MB);
  bf16_t* m1b = (bf16_t*)(ws + 108 * MB);  // 32MB
  bf16_t* m2b = (bf16_t*)(ws + 140 * MB);
  bf16_t* WkvT = (bf16_t*)(ws + 148 * MB);
  bf16_t* WqT = (bf16_t*)(ws + 152 * MB);
  bf16_t* WposT = (bf16_t*)(ws + 154 * MB);
  bf16_t* WprojT = (bf16_t*)(ws + 156 * MB);
  bf16_t* g1T[6], *g2T[6];
  for (int i = 0; i < 6; ++i) g1T[i] = (bf16_t*)(ws + (158 + 2 * (size_t)i) * MB);
  for (int i = 0; i < 6; ++i) g2T[i] = (bf16_t*)(ws + (170 + 2 * (size_t)i) * MB);
  bf16_t* W1T = (bf16_t*)(ws + 182 * MB);  // 8MB
  bf16_t* W2T = (bf16_t*)(ws + 190 * MB);  // 8MB  -> total 198MB

  auto wt = [&](const float* W, bf16_t* WT, int K, int N) {
    wt_transpose<<<dim3(N / 64, K / 64), 256, 0, stream>>>(W, WT, K, N);
  };
  wt(Wkv, WkvT, 1024, 2048);
  wt(Wq, WqT, 1024, 1024);
  wt(Wpos, WposT, 1024, 1024);
  wt(Wproj, WprojT, 1024, 1024);
  for (int i = 0; i < 6; ++i) wt(g1W[i], g1T[i], 1024, 1024);
  for (int i = 0; i < 6; ++i) wt(g2W[i], g2T[i], 1024, 1024);
  wt(mlp_W1, W1T, 1024, 4096);
  wt(mlp_W2, W2T, 4096, 1024);

  cvt_kernel<<<4096, 256, 0, stream>>>(inputs, inb, 1048576);
  cvt_kernel<<<1024, 256, 0, stream>>>(pos_emb, peb, 262144);

  ln_kernel<<<8192, 256, 0, stream>>>(memory, inputs, 4096, ln1_g, ln1_b, x1);

  auto gemm = [&](const bf16_t* A, const bf16_t* BT, float* Cf, bf16_t* Cb, const float* Cacc,
                  const float* bias, float bscale, int M, int N, int K, int act) {
    gemm_bf16<<<dim3(N / 128, M / 128), 256, 0, stream>>>(A, BT, Cf, Cb, Cacc, bias, bscale, M, N,
                                                          K, act);
  };

  gemm(x1, WkvT, nullptr, kvb, nullptr, bkv, 1.f, 8192, 2048, 1024, 0);
  gemm(x1 + (size_t)4096 * 1024, WqT, nullptr, qb, nullptr, bq, 1.f, 4096, 1024, 1024, 0);
  gemm(peb, WposT, nullptr, rposb, nullptr, bpos, 1.f, 1024, 1024, 1024, 0);
  vT_kernel<<<dim3(16, 128), 256, 0, stream>>>(kvb, vTb);
  attn_kernel<<<dim3(32, 16, 8), 256, 0, stream>>>(qb, kvb, rposb, vTb, u, v, avb);
  gemm(avb, WprojT, nullptr, a1b, nullptr, bproj, 1.f, 4096, 1024, 1024, 1);

  // GRU gate 1: x=inputs, y=a1
  gemm(a1b, g1T[0], rbuf, nullptr, nullptr, nullptr, 0.f, 4096, 1024, 1024, 0);
  gemm(inb, g1T[1], rbuf, nullptr, rbuf, nullptr, 0.f, 4096, 1024, 1024, 2);
  gemm(a1b, g1T[2], zbuf, nullptr, nullptr, nullptr, 0.f, 4096, 1024, 1024, 0);
  gemm(inb, g1T[3], zbuf, nullptr, zbuf, g1_bg, -1.f, 4096, 1024, 1024, 2);
  ew_rx_kernel<<<4096, 256, 0, stream>>>(rbuf, inputs, rxb, 1048576);
  gemm(a1b, g1T[4], hbuf, nullptr, nullptr, nullptr, 0.f, 4096, 1024, 1024, 0);
  gemm(rxb, g1T[5], hbuf, nullptr, hbuf, nullptr, 0.f, 4096, 1024, 1024, 3);
  ew_combine_kernel<<<4096, 256, 0, stream>>>(zbuf, hbuf, inputs, o1f, o1b, 1048576);

  ln_kernel<<<4096, 256, 0, stream>>>(o1f, nullptr, 1 << 30, ln2_g, ln2_b, x2b);
  gemm(x2b, W1T, nullptr, m1b, nullptr, mlp_b1, 1.f, 4096, 4096, 1024, 1);
  gemm(m1b, W2T, nullptr, m2b, nullptr, mlp_b2, 1.f, 4096, 1024, 4096, 1);

  // GRU gate 2: x=o1, y=m2
  gemm(m2b, g2T[0], rbuf, nullptr, nullptr, nullptr, 0.f, 4096, 1024, 1024, 0);
  gemm(o1b, g2T[1], rbuf, nullptr, rbuf, nullptr, 0.f, 4096, 1024, 1024, 2);
  gemm(m2b, g2T[2], zbuf, nullptr, nullptr, nullptr, 0.f, 4096, 1024, 1024, 0);
  gemm(o1b, g2T[3], zbuf, nullptr, zbuf, g2_bg, -1.f, 4096, 1024, 1024, 2);
  ew_rx_kernel<<<4096, 256, 0, stream>>>(rbuf, o1f, rxb, 1048576);
  gemm(m2b, g2T[4], hbuf, nullptr, nullptr, nullptr, 0.f, 4096, 1024, 1024, 0);
  gemm(rxb, g2T[5], hbuf, nullptr, hbuf, nullptr, 0.f, 4096, 1024, 1024, 3);
  ew_combine_kernel<<<4096, 256, 0, stream>>>(zbuf, hbuf, o1f, (float*)d_out, nullptr, 1048576);
}

// Round 2
// 968.892 us; speedup vs baseline: 1.1522x; 1.1522x over previous
//
#include <hip/hip_runtime.h>

// GTrXL fused pipeline v2: XCD-aware GEMM swizzle, fused GRU epilogues,
// restructured attention (32-row s-tile, LDS-chunked K/rpos, L2-friendly grid).

typedef __bf16 bf16_t;
typedef __bf16 bf16x4 __attribute__((ext_vector_type(4)));
typedef __bf16 bf16x8 __attribute__((ext_vector_type(8)));
typedef float f32x4 __attribute__((ext_vector_type(4)));

typedef __attribute__((address_space(1))) const void* GPtr;
typedef __attribute__((address_space(3))) void* LPtr;

// ---------------- fp32 -> bf16 convert ----------------
__global__ __launch_bounds__(256) void cvt_kernel(const float* __restrict__ in,
                                                  bf16_t* __restrict__ out, int n4) {
  int i = blockIdx.x * 256 + threadIdx.x;
  if (i >= n4) return;
  f32x4 v = ((const f32x4*)in)[i];
  bf16x4 o;
  o[0] = (bf16_t)v[0]; o[1] = (bf16_t)v[1]; o[2] = (bf16_t)v[2]; o[3] = (bf16_t)v[3];
  ((bf16x4*)out)[i] = o;
}

// ---------------- batched weight transpose: W[K][N] f32 -> WT[N][K] bf16 ----------------
struct WtArgs {
  const float* src[18];
  bf16_t* dst[18];
  int kdim[18];
  int ndim[18];
  int tile_end[18];
};

__global__ __launch_bounds__(256) void wt_batch(WtArgs a) {
  int t = blockIdx.x;
  int i = 0;
  while (i < 17 && t >= a.tile_end[i]) ++i;
  int lt = t - (i ? a.tile_end[i - 1] : 0);
  const float* W = a.src[i];
  bf16_t* WT = a.dst[i];
  int K = a.kdim[i], N = a.ndim[i];
  int ntx = N >> 6;
  int n0 = (lt % ntx) * 64, k0 = (lt / ntx) * 64;
  __shared__ float tbuf[64][65];
  int tid = threadIdx.x;
  int c = tid & 63, r0 = tid >> 6;
  #pragma unroll
  for (int p = 0; p < 16; ++p) {
    int r = r0 + p * 4;
    tbuf[r][c] = W[(size_t)(k0 + r) * N + n0 + c];
  }
  __syncthreads();
  #pragma unroll
  for (int p = 0; p < 16; ++p) {
    int r = r0 + p * 4;  // r = n index, c = k index
    WT[(size_t)(n0 + r) * K + k0 + c] = (bf16_t)tbuf[c][r];
  }
}

// ---------------- LayerNorm over D=1024, optional row-concat of two sources ----------------
__global__ __launch_bounds__(256) void ln_kernel(const float* __restrict__ srcA,
                                                 const float* __restrict__ srcB, int splitRow,
                                                 const float* __restrict__ g,
                                                 const float* __restrict__ be,
                                                 bf16_t* __restrict__ out) {
  const int row = blockIdx.x, tid = threadIdx.x;
  const float* src = (srcB != nullptr && row >= splitRow)
                         ? srcB + (size_t)(row - splitRow) * 1024
                         : srcA + (size_t)row * 1024;
  f32x4 x = ((const f32x4*)src)[tid];
  __shared__ float red[8];
  float s = x[0] + x[1] + x[2] + x[3];
  #pragma unroll
  for (int o = 32; o; o >>= 1) s += __shfl_down(s, o);
  if ((tid & 63) == 0) red[tid >> 6] = s;
  __syncthreads();
  if (tid == 0) red[4] = (red[0] + red[1] + red[2] + red[3]) * (1.f / 1024.f);
  __syncthreads();
  const float mean = red[4];
  f32x4 d = x - mean;
  float s2 = d[0] * d[0] + d[1] * d[1] + d[2] * d[2] + d[3] * d[3];
  #pragma unroll
  for (int o = 32; o; o >>= 1) s2 += __shfl_down(s2, o);
  if ((tid & 63) == 0) red[tid >> 6] = s2;
  __syncthreads();
  if (tid == 0) red[5] = rsqrtf((red[0] + red[1] + red[2] + red[3]) * (1.f / 1024.f) + 1e-5f);
  __syncthreads();
  const float rstd = red[5];
  f32x4 gg = ((const f32x4*)g)[tid], bb = ((const f32x4*)be)[tid];
  bf16x4 o4;
  #pragma unroll
  for (int j = 0; j < 4; ++j) o4[j] = (bf16_t)(d[j] * rstd * gg[j] + bb[j]);
  ((bf16x4*)(out + (size_t)row * 1024))[tid] = o4;
}

// ---------------- generic bf16 MFMA GEMM with fused epilogues ----------------
// act: 0 none, 1 relu, 4 gate_rz (N=2048: cols<1024 -> rx=sigmoid(v+acc)*x -> Cb;
//      cols>=1024 -> z=sigmoid(v+acc-bias) -> Cf), 5 gate_combine
//      (h=tanh(v+acc); o=x+z*(h-x) -> Cf [+Cb])
__global__ __launch_bounds__(256) void gemm_bf16(const bf16_t* __restrict__ A,
                                                 const bf16_t* __restrict__ BT,
                                                 const float* __restrict__ bias,
                                                 float* __restrict__ Cf, bf16_t* __restrict__ Cb,
                                                 const float* __restrict__ Cacc, int ldacc,
                                                 const float* __restrict__ xin,
                                                 const float* __restrict__ zin,
                                                 int M, int N, int K, int act) {
  __shared__ bf16_t As[128 * 32];
  __shared__ bf16_t Bs[128 * 32];
  const int tid = threadIdx.x, lane = tid & 63, wid = tid >> 6;
  // bijective XCD-chunk swizzle: each XCD owns contiguous tile_m band (A reuse in L2)
  const int nx = gridDim.x;
  int flat = blockIdx.y * nx + blockIdx.x;
  int nwg = nx * gridDim.y;
  int q8 = nwg >> 3, r8 = nwg & 7;
  int xcd = flat & 7, idx = flat >> 3;
  int wg = (xcd < r8) ? xcd * (q8 + 1) + idx : r8 * (q8 + 1) + (xcd - r8) * q8 + idx;
  const int m0 = (wg / nx) * 128, n0 = (wg % nx) * 128;
  const int wm = (wid >> 1) * 64, wn = (wid & 1) * 64;
  const int mrow = lane & 15, kq = lane >> 4;
  f32x4 acc[4][4] = {};
  for (int k0 = 0; k0 < K; k0 += 32) {
    #pragma unroll
    for (int p = 0; p < 2; ++p) {
      int cbase = p * 256 + wid * 64;
      int c = cbase + lane;
      const bf16_t* ga = A + (size_t)(m0 + (c >> 2)) * K + k0 + (c & 3) * 8;
      const bf16_t* gb = BT + (size_t)(n0 + (c >> 2)) * K + k0 + (c & 3) * 8;
      __builtin_amdgcn_global_load_lds((GPtr)ga, (LPtr)(&As[cbase * 8]), 16, 0, 0);
      __builtin_amdgcn_global_load_lds((GPtr)gb, (LPtr)(&Bs[cbase * 8]), 16, 0, 0);
    }
    __syncthreads();
    bf16x8 af[4], bfr[4];
    #pragma unroll
    for (int i = 0; i < 4; ++i) {
      af[i] = *(const bf16x8*)&As[(wm + i * 16 + mrow) * 32 + kq * 8];
      bfr[i] = *(const bf16x8*)&Bs[(wn + i * 16 + mrow) * 32 + kq * 8];
    }
    #pragma unroll
    for (int i = 0; i < 4; ++i)
      #pragma unroll
      for (int j = 0; j < 4; ++j)
        acc[i][j] = __builtin_amdgcn_mfma_f32_16x16x32_bf16(af[i], bfr[j], acc[i][j], 0, 0, 0);
    __syncthreads();
  }
  #pragma unroll
  for (int i = 0; i < 4; ++i) {
    #pragma unroll
    for (int j = 0; j < 4; ++j) {
      int colb = n0 + wn + j * 16 + mrow;
      #pragma unroll
      for (int r2 = 0; r2 < 4; ++r2) {
        int row = m0 + wm + i * 16 + kq * 4 + r2;
        float vv = acc[i][j][r2];
        if (act <= 1) {
          if (bias) vv += bias[colb];
          if (act == 1) vv = fmaxf(vv, 0.f);
          size_t idxN = (size_t)row * N + colb;
          if (Cf) Cf[idxN] = vv;
          if (Cb) Cb[idxN] = (bf16_t)vv;
        } else if (act == 4) {
          vv += Cacc[(size_t)row * ldacc + colb];
          if (colb < 1024) {
            float r = 1.f / (1.f + __expf(-vv));
            Cb[(size_t)row * 1024 + colb] = (bf16_t)(r * xin[(size_t)row * 1024 + colb]);
          } else {
            float z = 1.f / (1.f + __expf(-(vv - bias[colb - 1024])));
            Cf[(size_t)row * 1024 + colb - 1024] = z;
          }
        } else {  // act == 5
          vv += Cacc[(size_t)row * ldacc + colb];
          float hh = tanhf(vv);
          size_t e = (size_t)row * 1024 + colb;
          float xx = xin[e], zz = zin[e];
          float o = xx + zz * (hh - xx);
          Cf[e] = o;
          if (Cb) Cb[e] = (bf16_t)o;
        }
      }
    }
  }
}

// ---------------- value transpose: kv val-half -> vT[(b*16+h)*64+d][f] ----------------
__global__ __launch_bounds__(256) void vT_kernel(const bf16_t* __restrict__ kv,
                                                 bf16_t* __restrict__ vT) {
  int ft = blockIdx.x;  // 16 tiles of 64 f
  int bh = blockIdx.y;  // b*16+h
  int b = bh >> 4, h = bh & 15;
  __shared__ bf16_t t[64][68];
  int tid = threadIdx.x;
  {
    int dq = (tid & 15) * 4, fr = tid >> 4;
    #pragma unroll
    for (int p = 0; p < 4; ++p) {
      int fi = fr + p * 16;
      const bf16_t* src = kv + ((size_t)((ft * 64 + fi) * 8 + b)) * 2048 + 1024 + h * 64 + dq;
      *(bf16x4*)&t[fi][dq] = *(const bf16x4*)src;
    }
  }
  __syncthreads();
  {
    int fl = tid & 63, dr = tid >> 6;
    #pragma unroll
    for (int p = 0; p < 16; ++p) {
      int d = dr + p * 4;
      vT[((size_t)(bh * 64 + d)) * 1024 + ft * 64 + fl] = t[fl][d];
    }
  }
}

// ---------------- fused rel-pos attention v2 ----------------
// grid(x=bh=128, y=st=16): all st-blocks of a (b,h) land on XCD bh%8 -> key/V L2 reuse.
// 512 threads (8 waves), 32-row s-tile. K/rpos staged in XOR-swizzled LDS chunks.
#define SC_RS 1032
__global__ __launch_bounds__(512) void attn_kernel(const bf16_t* __restrict__ q,
                                                   const bf16_t* __restrict__ kv,
                                                   const bf16_t* __restrict__ rpos,
                                                   const bf16_t* __restrict__ vT,
                                                   const float* __restrict__ u,
                                                   const float* __restrict__ v,
                                                   bf16_t* __restrict__ av) {
  const int bh = blockIdx.x, st = blockIdx.y;
  const int b = bh >> 4, h = bh & 15;
  const int s0 = st * 32;
  const int tid = threadIdx.x, lane = tid & 63, w = tid >> 6;
  const int mrow = lane & 15, kq = lane >> 4;
  const int sb = w & 1, fg = w >> 1;  // s-band (0/1), f-tile group (0..3)

  __shared__ bf16_t sc[32 * SC_RS];        // 66KB score/prob matrix
  __shared__ bf16_t chunk[2][128 * 64];    // 32KB dbuf K/rpos chunks (XOR-swizzled cols)
  __shared__ bf16_t qu[32][72], qv[32][72];
  __shared__ float rrecip[32];

  {  // stage qu/qv = (q + u|v) * SCALE
    int sl = tid >> 4, dq = (tid & 15) * 4;
    const bf16_t* qp = q + ((size_t)((s0 + sl) * 8 + b)) * 1024 + h * 64 + dq;
    bf16x4 q4 = *(const bf16x4*)qp;
    f32x4 uu = *(const f32x4*)(u + h * 64 + dq);
    f32x4 vv = *(const f32x4*)(v + h * 64 + dq);
    #pragma unroll
    for (int j = 0; j < 4; ++j) {
      float qf = (float)q4[j];
      qu[sl][dq + j] = (bf16_t)((qf + uu[j]) * 0.125f);
      qv[sl][dq + j] = (bf16_t)((qf + vv[j]) * 0.125f);
    }
  }

  // stage one 128-row chunk (wave w -> rows w*16..+16); source cols pre-XOR-swizzled
  auto stage = [&](const bf16_t* base, size_t rstride, int f0, int bufi) {
    #pragma unroll
    for (int li = 0; li < 2; ++li) {
      int r = w * 16 + li * 8 + (lane >> 3);
      int cbx = ((lane & 7) * 16) ^ ((r & 7) << 4);
      const bf16_t* src = base + (size_t)(f0 + r) * rstride + (cbx >> 1);
      __builtin_amdgcn_global_load_lds((GPtr)src, (LPtr)(&chunk[bufi][w * 1024 + li * 512]), 16,
                                       0, 0);
    }
  };
  const bf16_t* kbase = kv + (size_t)b * 2048 + h * 64;  // f-row stride 16384
  const bf16_t* rbase = rpos + h * 64;                   // j-row stride 1024

  stage(kbase, 16384, 0, 0);
  __syncthreads();

  bf16x8 afu[2], afv[2];
  #pragma unroll
  for (int kh = 0; kh < 2; ++kh) {
    afu[kh] = *(const bf16x8*)&qu[sb * 16 + mrow][kh * 32 + kq * 8];
    afv[kh] = *(const bf16x8*)&qv[sb * 16 + mrow][kh * 32 + kq * 8];
  }

  // phase 1: content scores sc[s][f] = (q+u)*k
  for (int c = 0; c < 8; ++c) {
    if (c < 7) stage(kbase, 16384, (c + 1) * 128, (c + 1) & 1);
    const bf16_t* cb = chunk[c & 1];
    #pragma unroll
    for (int t = 0; t < 2; ++t) {
      int ft = fg * 2 + t;
      int rr = ft * 16 + mrow;
      int sw = (mrow & 7) << 4;
      bf16x8 b0 = *(const bf16x8*)&cb[rr * 64 + (((kq * 16) ^ sw) >> 1)];
      bf16x8 b1 = *(const bf16x8*)&cb[rr * 64 + (((64 + kq * 16) ^ sw) >> 1)];
      f32x4 cc = {0.f, 0.f, 0.f, 0.f};
      cc = __builtin_amdgcn_mfma_f32_16x16x32_bf16(afu[0], b0, cc, 0, 0, 0);
      cc = __builtin_amdgcn_mfma_f32_16x16x32_bf16(afu[1], b1, cc, 0, 0, 0);
      #pragma unroll
      for (int r2 = 0; r2 < 4; ++r2)
        sc[(sb * 16 + kq * 4 + r2) * SC_RS + c * 128 + ft * 16 + mrow] = (bf16_t)cc[r2];
    }
    __syncthreads();
  }

  // phase 2: position scores, rel-shift scatter-add: f = j - 511 + s
  stage(rbase, 1024, 0, 0);
  __syncthreads();
  for (int c = 0; c < 8; ++c) {
    if (c < 7) stage(rbase, 1024, (c + 1) * 128, (c + 1) & 1);
    const bf16_t* cb = chunk[c & 1];
    #pragma unroll
    for (int t = 0; t < 2; ++t) {
      int ft = fg * 2 + t;
      int rr = ft * 16 + mrow;
      int sw = (mrow & 7) << 4;
      bf16x8 b0 = *(const bf16x8*)&cb[rr * 64 + (((kq * 16) ^ sw) >> 1)];
      bf16x8 b1 = *(const bf16x8*)&cb[rr * 64 + (((64 + kq * 16) ^ sw) >> 1)];
      f32x4 cc = {0.f, 0.f, 0.f, 0.f};
      cc = __builtin_amdgcn_mfma_f32_16x16x32_bf16(afv[0], b0, cc, 0, 0, 0);
      cc = __builtin_amdgcn_mfma_f32_16x16x32_bf16(afv[1], b1, cc, 0, 0, 0);
      #pragma unroll
      for (int r2 = 0; r2 < 4; ++r2) {
        int srow = sb * 16 + kq * 4 + r2;
        int f = (c * 128 + ft * 16 + mrow) - 511 + s0 + srow;
        if (f >= 0 && f < 1024) {
          float old = (float)sc[srow * SC_RS + f];
          sc[srow * SC_RS + f] = (bf16_t)(old + cc[r2]);
        }
      }
    }
    __syncthreads();
  }

  // phase 3: masked softmax, wave w owns rows 4w..4w+3; vectorized bf16x8
  for (int rr = 0; rr < 4; ++rr) {
    int row = w * 4 + rr;
    int fmx = s0 + row + 512;
    bf16x8 p0 = *(const bf16x8*)&sc[row * SC_RS + lane * 16];
    bf16x8 p1 = *(const bf16x8*)&sc[row * SC_RS + lane * 16 + 8];
    float vals[16];
    float mx = -1e30f;
    #pragma unroll
    for (int i = 0; i < 8; ++i) {
      vals[i] = (float)p0[i];
      vals[8 + i] = (float)p1[i];
    }
    #pragma unroll
    for (int i = 0; i < 16; ++i) {
      if (lane * 16 + i <= fmx) mx = fmaxf(mx, vals[i]);
    }
    #pragma unroll
    for (int o = 32; o; o >>= 1) mx = fmaxf(mx, __shfl_xor(mx, o));
    float sum = 0.f;
    bf16x8 e0, e1;
    #pragma unroll
    for (int i = 0; i < 16; ++i) {
      float e = (lane * 16 + i <= fmx) ? __expf(vals[i] - mx) : 0.f;
      sum += e;
      if (i < 8) e0[i] = (bf16_t)e; else e1[i - 8] = (bf16_t)e;
    }
    *(bf16x8*)&sc[row * SC_RS + lane * 16] = e0;
    *(bf16x8*)&sc[row * SC_RS + lane * 16 + 8] = e1;
    #pragma unroll
    for (int o = 32; o; o >>= 1) sum += __shfl_xor(sum, o);
    if (lane == 0) rrecip[row] = 1.f / sum;
  }
  __syncthreads();

  // phase 4: AV. wave w -> s-band w&1, d-tile w>>1. B from vT (L2-resident).
  {
    int dt = fg;
    const bf16_t* vp = vT + ((size_t)(bh * 64 + dt * 16 + mrow)) * 1024;
    f32x4 acc = {0.f, 0.f, 0.f, 0.f};
    for (int kk = 0; kk < 32; ++kk) {
      bf16x8 af = *(const bf16x8*)&sc[(sb * 16 + mrow) * SC_RS + kk * 32 + kq * 8];
      bf16x8 bv = *(const bf16x8*)(vp + kk * 32 + kq * 8);
      acc = __builtin_amdgcn_mfma_f32_16x16x32_bf16(af, bv, acc, 0, 0, 0);
    }
    #pragma unroll
    for (int r2 = 0; r2 < 4; ++r2) {
      int srow = sb * 16 + kq * 4 + r2;
      float ov = acc[r2] * rrecip[srow];
      av[((size_t)((s0 + srow) * 8 + b)) * 1024 + h * 64 + dt * 16 + mrow] = (bf16_t)ov;
    }
  }
}

// ---------------- host ----------------
extern "C" void kernel_launch(void* const* d_in, const int* in_sizes, int n_in,
                              void* d_out, int out_size, void* d_ws, size_t ws_size,
                              hipStream_t stream) {
  const float* inputs = (const float*)d_in[0];
  const float* pos_emb = (const float*)d_in[1];
  const float* memory = (const float*)d_in[2];
  const float* u = (const float*)d_in[3];
  const float* v = (const float*)d_in[4];
  const float* Wkv = (const float*)d_in[6];
  const float* bkv = (const float*)d_in[7];
  const float* Wq = (const float*)d_in[8];
  const float* bq = (const float*)d_in[9];
  const float* Wpos = (const float*)d_in[10];
  const float* bpos = (const float*)d_in[11];
  const float* Wproj = (const float*)d_in[12];
  const float* bproj = (const float*)d_in[13];
  const float* ln1_g = (const float*)d_in[14];
  const float* ln1_b = (const float*)d_in[15];
  const float* ln2_g = (const float*)d_in[16];
  const float* ln2_b = (const float*)d_in[17];
  const float* g1_bg = (const float*)d_in[24];
  const float* g2_bg = (const float*)d_in[31];
  const float* mlp_W1 = (const float*)d_in[32];
  const float* mlp_b1 = (const float*)d_in[33];
  const float* mlp_W2 = (const float*)d_in[34];
  const float* mlp_b2 = (const float*)d_in[35];

  char* ws = (char*)d_ws;
  const size_t MB = 1ull << 20;
  // attn-phase region
  bf16_t* x1 = (bf16_t*)(ws + 0);            // 16MB
  bf16_t* kvb = (bf16_t*)(ws + 16 * MB);     // 32MB
  bf16_t* qb = (bf16_t*)(ws + 48 * MB);      // 8MB
  bf16_t* peb = (bf16_t*)(ws + 56 * MB);     // 2MB
  bf16_t* rposb = (bf16_t*)(ws + 58 * MB);   // 2MB
  bf16_t* vTb = (bf16_t*)(ws + 60 * MB);     // 16MB
  bf16_t* avb = (bf16_t*)(ws + 76 * MB);     // 8MB
  bf16_t* a1b = (bf16_t*)(ws + 84 * MB);     // 8MB (dead after G1 of gate1)
  bf16_t* inb = (bf16_t*)(ws + 92 * MB);     // 8MB (dead after G2 of gate1)
  // gate-phase region (aliases the above; lifetimes verified)
  float* rzh = (float*)(ws + 0);             // 48MB 4096x3072
  float* zbuf = (float*)(ws + 48 * MB);      // 16MB
  bf16_t* rxb = (bf16_t*)(ws + 64 * MB);     // 8MB
  float* o1f = (float*)(ws + 72 * MB);       // 16MB
  bf16_t* o1b = (bf16_t*)(ws + 88 * MB);     // 8MB
  bf16_t* x2b = (bf16_t*)(ws + 96 * MB);     // 8MB
  bf16_t* m1b = (bf16_t*)(ws + 104 * MB);    // 32MB
  bf16_t* m2b = (bf16_t*)(ws + 136 * MB);    // 8MB
  // weights (bf16, transposed)
  bf16_t* WkvT = (bf16_t*)(ws + 144 * MB);
  bf16_t* WqT = (bf16_t*)(ws + 148 * MB);
  bf16_t* WposT = (bf16_t*)(ws + 150 * MB);
  bf16_t* WprojT = (bf16_t*)(ws + 152 * MB);
  bf16_t* g1cat3 = (bf16_t*)(ws + 154 * MB);  // [Wr;Wz;Wg]^T rows 0..3071
  bf16_t* g1cat2 = (bf16_t*)(ws + 160 * MB);  // [Ur;Uz]^T rows 0..2047
  bf16_t* g1ug = (bf16_t*)(ws + 164 * MB);
  bf16_t* g2cat3 = (bf16_t*)(ws + 166 * MB);
  bf16_t* g2cat2 = (bf16_t*)(ws + 172 * MB);
  bf16_t* g2ug = (bf16_t*)(ws + 176 * MB);
  bf16_t* W1T = (bf16_t*)(ws + 178 * MB);  // 8MB
  bf16_t* W2T = (bf16_t*)(ws + 186 * MB);  // 8MB -> 194MB total

  // batched weight transpose: 18 entries
  WtArgs wa;
  const float* srcs[18] = {Wkv, Wq, Wpos, Wproj,
                           (const float*)d_in[18], (const float*)d_in[20], (const float*)d_in[22],
                           (const float*)d_in[19], (const float*)d_in[21], (const float*)d_in[23],
                           (const float*)d_in[25], (const float*)d_in[27], (const float*)d_in[29],
                           (const float*)d_in[26], (const float*)d_in[28], (const float*)d_in[30],
                           mlp_W1, mlp_W2};
  bf16_t* dsts[18] = {WkvT, WqT, WposT, WprojT,
                      g1cat3, g1cat3 + 1024 * 1024, g1cat3 + 2 * 1024 * 1024,
                      g1cat2, g1cat2 + 1024 * 1024, g1ug,
                      g2cat3, g2cat3 + 1024 * 1024, g2cat3 + 2 * 1024 * 1024,
                      g2cat2, g2cat2 + 1024 * 1024, g2ug,
                      W1T, W2T};
  int kds[18] = {1024, 1024, 1024, 1024, 1024, 1024, 1024, 1024, 1024,
                 1024, 1024, 1024, 1024, 1024, 1024, 1024, 1024, 4096};
  int nds[18] = {2048, 1024, 1024, 1024, 1024, 1024, 1024, 1024, 1024,
                 1024, 1024, 1024, 1024, 1024, 1024, 1024, 4096, 1024};
  int cum = 0;
  for (int i = 0; i < 18; ++i) {
    wa.src[i] = srcs[i];
    wa.dst[i] = dsts[i];
    wa.kdim[i] = kds[i];
    wa.ndim[i] = nds[i];
    cum += (nds[i] >> 6) * (kds[i] >> 6);
    wa.tile_end[i] = cum;
  }
  wt_batch<<<cum, 256, 0, stream>>>(wa);

  cvt_kernel<<<4096, 256, 0, stream>>>(inputs, inb, 1048576);
  cvt_kernel<<<1024, 256, 0, stream>>>(pos_emb, peb, 262144);
  ln_kernel<<<8192, 256, 0, stream>>>(memory, inputs, 4096, ln1_g, ln1_b, x1);

  auto gemm = [&](const bf16_t* A, const bf16_t* BT, const float* bias, float* Cf, bf16_t* Cb,
                  const float* Cacc, int ldacc, const float* xin, const float* zin, int M, int N,
                  int K, int act) {
    gemm_bf16<<<dim3(N / 128, M / 128), 256, 0, stream>>>(A, BT, bias, Cf, Cb, Cacc, ldacc, xin,
                                                          zin, M, N, K, act);
  };

  gemm(x1, WkvT, bkv, nullptr, kvb, nullptr, 0, nullptr, nullptr, 8192, 2048, 1024, 0);
  gemm(x1 + (size_t)4096 * 1024, WqT, bq, nullptr, qb, nullptr, 0, nullptr, nullptr, 4096, 1024,
       1024, 0);
  gemm(peb, WposT, bpos, nullptr, rposb, nullptr, 0, nullptr, nullptr, 1024, 1024, 1024, 0);
  vT_kernel<<<dim3(16, 128), 256, 0, stream>>>(kvb, vTb);
  attn_kernel<<<dim3(128, 16), 512, 0, stream>>>(qb, kvb, rposb, vTb, u, v, avb);
  gemm(avb, WprojT, bproj, nullptr, a1b, nullptr, 0, nullptr, nullptr, 4096, 1024, 1024, 1);

  // GRU gate 1: x=inputs(f32)/inb(bf16), y=a1b
  gemm(a1b, g1cat3, nullptr, rzh, nullptr, nullptr, 0, nullptr, nullptr, 4096, 3072, 1024, 0);
  gemm(inb, g1cat2, g1_bg, zbuf, rxb, rzh, 3072, inputs, nullptr, 4096, 2048, 1024, 4);
  gemm(rxb, g1ug, nullptr, o1f, o1b, rzh + 2048, 3072, inputs, zbuf, 4096, 1024, 1024, 5);

  ln_kernel<<<4096, 256, 0, stream>>>(o1f, nullptr, 1 << 30, ln2_g, ln2_b, x2b);
  gemm(x2b, W1T, mlp_b1, nullptr, m1b, nullptr, 0, nullptr, nullptr, 4096, 4096, 1024, 1);
  gemm(m1b, W2T, mlp_b2, nullptr, m2b, nullptr, 0, nullptr, nullptr, 4096, 1024, 4096, 1);

  // GRU gate 2: x=o1f/o1b, y=m2b
  gemm(m2b, g2cat3, nullptr, rzh, nullptr, nullptr, 0, nullptr, nullptr, 4096, 3072, 1024, 0);
  gemm(o1b, g2cat2, g2_bg, zbuf, rxb, rzh, 3072, o1f, nullptr, 4096, 2048, 1024, 4);
  gemm(rxb, g2ug, nullptr, (float*)d_out, nullptr, rzh + 2048, 3072, o1f, zbuf, 4096, 1024, 1024,
       5);
}